// Round 1
// baseline (503.696 us; speedup 1.0000x reference)
//
#include <hip/hip_runtime.h>
#include <hip/hip_bf16.h>
#include <stdint.h>
#include <stddef.h>

// ---------------------------------------------------------------------------
// Connectivity3D: PointNet (6->64->128->256, BN folded, max-pool) ->
// object_embedding -> 2x GCN -> edge MLP -> tanh -> [512,16,16].
//
// Algebraic collapse: dense intra-object edges => deg=16 for every node =>
// GCN output = (per-object mean of xw) + b, identical for all 16 parts =>
// ONE edge score per object; only fsum[obj] = sum_parts feat is needed.
//
// R9 = software-pipelined chunk loop: 2 barriers/iter instead of 3.
//   Phase A: L2(cg) (h1->h2) + stage x(cg+1)        | barrier
//   Phase B: L1(cg+1) (x->h1) + L3(cg) (h2->macc)   | barrier
// h1/h2/x all stay SINGLE-buffered (L1 writes h1 while L3 reads h2; x is
// staged one phase ahead), so LDS stays 62 KB -> 2 blocks/CU. Barriers
// drop 193->131 and L1's MFMAs land inside the MFMA-dense L3 phase,
// letting the scheduler overlap LDS reads / MFMA / VALU across waves.
// MFMA floor ~417K cyc/CU, LDS-read floor ~426K cyc/CU; measured 920K at
// MfmaUtil 43% + VALUBusy 39% => serialization, not a pipe, is the limit.
// ---------------------------------------------------------------------------

typedef short bf16x8 __attribute__((ext_vector_type(8)));
typedef short bf16x4 __attribute__((ext_vector_type(4)));
typedef float f32x4  __attribute__((ext_vector_type(4)));

// workspace byte offsets (all 16B aligned)
#define WT1_OFF   0u        // bf16 [64][32]  (W1*g1)^T, col6 = bias, cols7-31 = 0
#define WT2_OFF   4096u     // bf16 [128][64] (W2*g2)^T
#define WT3_OFF   20480u    // bf16 [256][128](W3*g3)^T
#define B1F_OFF   86016u    // f32 [64] (unused; layout keep)
#define B2F_OFF   86272u    // f32 [128]
#define B3F_OFF   86784u    // f32 [256]

__device__ __forceinline__ unsigned short f2bf(float f) {
  union { float f; unsigned u; } v; v.f = f;
  unsigned r = v.u + 0x7fffu + ((v.u >> 16) & 1u);   // round-to-nearest-even
  return (unsigned short)(r >> 16);
}

__device__ __forceinline__ bf16x4 pack_relu4(f32x4 d) {
  __hip_bfloat162 lo = __float22bfloat162_rn(make_float2(fmaxf(d.x, 0.f), fmaxf(d.y, 0.f)));
  __hip_bfloat162 hi = __float22bfloat162_rn(make_float2(fmaxf(d.z, 0.f), fmaxf(d.w, 0.f)));
  union { bf16x4 v; __hip_bfloat162 h[2]; } u;
  u.h[0] = lo; u.h[1] = hi;
  return u.v;
}

// ---------------------------------------------------------------------------
__global__ void prep_kernel(
    const float* __restrict__ W1, const float* __restrict__ b1,
    const float* __restrict__ g1, const float* __restrict__ bt1,
    const float* __restrict__ W2, const float* __restrict__ b2,
    const float* __restrict__ g2, const float* __restrict__ bt2,
    const float* __restrict__ W3, const float* __restrict__ b3,
    const float* __restrict__ g3, const float* __restrict__ bt3,
    unsigned char* __restrict__ ws)
{
  unsigned short* wt1 = (unsigned short*)(ws + WT1_OFF);
  unsigned short* wt2 = (unsigned short*)(ws + WT2_OFF);
  unsigned short* wt3 = (unsigned short*)(ws + WT3_OFF);
  float* b1f  = (float*)(ws + B1F_OFF);
  float* b2f  = (float*)(ws + B2F_OFF);
  float* b3f  = (float*)(ws + B3F_OFF);

  int i = blockIdx.x * 256 + threadIdx.x;
  if (i < 2048) { int o = i >> 5, c = i & 31;                 // wt1[o][c]
    float v = (c < 6) ? W1[c*64 + o] * g1[o]
            : (c == 6 ? (b1[o]*g1[o] + bt1[o]) : 0.f);        // bias-in-col6
    wt1[i] = f2bf(v); return; }
  i -= 2048;
  if (i < 8192) { int o = i >> 6, c = i & 63;                 // wt2[o][c]
    wt2[i] = f2bf(W2[c*128 + o] * g2[o]); return; }
  i -= 8192;
  if (i < 32768) { int o = i >> 7, c = i & 127;               // wt3[o][c]
    wt3[i] = f2bf(W3[c*256 + o] * g3[o]); return; }
  i -= 32768;
  if (i < 64)  { b1f[i] = b1[i]*g1[i] + bt1[i]; return; }
  i -= 64;
  if (i < 128) { b2f[i] = b2[i]*g2[i] + bt2[i]; return; }
  i -= 128;
  if (i < 256) { b3f[i] = b3[i]*g3[i] + bt3[i]; }
}

// ---------------------------------------------------------------------------
// One block per object: 512 blocks x 512 thr (8 waves), 8192 pts, chunk=128,
// 64 iterations, 2 barriers/iter (R9 pipelined). Then in-block MLP epilogue
// (per-object GCN+connectivity head) and direct out write.
// LDS [pt][ch] bf16: x[128][40] @0, h1[128][72] @5120, h2[128][136] @14336
#define LDSX  0
#define LDSH1 5120
#define LDSH2 14336

__global__ __launch_bounds__(512)
__attribute__((amdgpu_waves_per_eu(4, 4)))
void pointnet_fused_kernel(
    const float* __restrict__ pcls, const unsigned char* __restrict__ ws,
    const float* __restrict__ We,  const float* __restrict__ be,
    const float* __restrict__ Wg1, const float* __restrict__ bg1,
    const float* __restrict__ Wg2, const float* __restrict__ bg2,
    const float* __restrict__ Wc1, const float* __restrict__ bc1,
    const float* __restrict__ Wc2, const float* __restrict__ bc2,
    const float* __restrict__ Wc3, const float* __restrict__ bc3,
    float* __restrict__ out)
{
  __shared__ __align__(16) unsigned short lds[31744];   // 62 KB -> 2 blocks/CU

  const unsigned short* wt1 = (const unsigned short*)(ws + WT1_OFF);
  const unsigned short* wt2 = (const unsigned short*)(ws + WT2_OFF);
  const unsigned short* wt3 = (const unsigned short*)(ws + WT3_OFF);
  const float* b2f = (const float*)(ws + B2F_OFF);
  const float* b3f = (const float*)(ws + B3F_OFF);

  const int tid  = threadIdx.x;
  const int w    = tid >> 6;        // wave 0..7
  const int lane = tid & 63;
  const int l15  = lane & 15;
  const int q    = lane >> 4;       // quad 0..3
  const int obj  = blockIdx.x;

  const int c1t = w & 3;            // L1 ch-tile
  const int ph  = w >> 2;           // L1 pt-half

  // Weight A-fragments, register-resident. A[m=l15][k=q*8+j].
  bf16x8 af1 = *(const bf16x8*)(wt1 + (c1t*16 + l15)*32 + q*8);
  bf16x8 af2[2], af3[2][4];
#pragma unroll
  for (int kf = 0; kf < 2; ++kf)
    af2[kf] = *(const bf16x8*)(wt2 + (w*16 + l15)*64 + kf*32 + q*8);
#pragma unroll
  for (int nt = 0; nt < 2; ++nt)
#pragma unroll
    for (int kf = 0; kf < 4; ++kf)
      af3[nt][kf] = *(const bf16x8*)(wt3 + ((2*w + nt)*16 + l15)*128 + kf*32 + q*8);

  const f32x4 bias2 = *(const f32x4*)(b2f + w*16 + q*4);

  // point staging: 768 floats/chunk; thread covers i=tid, (tid<256) i=512+tid
  const int i1v = tid < 256;
  int p0 = tid / 6,          c0 = tid - 6*p0;
  int p1 = (512 + tid) / 6,  c1 = (512 + tid) - 6*p1;
  const int soff0 = LDSX + p0*40 + c0;
  const int soff1 = LDSX + p1*40 + c1;

  // init x: zeros, col6 = 1.0 (bias channel), cols 7..31 stay 0
  for (int i = tid; i < 5120; i += 512) lds[i] = 0;
  __syncthreads();
  if (tid < 128) lds[LDSX + tid*40 + 6] = 0x3F80;   // bf16 1.0 (disjoint from x data cols)

  const float* pbase = pcls + (size_t)obj * 49152;   // 8192 pts * 6
  lds[soff0] = f2bf(pbase[tid]);
  if (i1v) lds[soff1] = f2bf(pbase[512 + tid]);
  __syncthreads();

  f32x4 macc[2];
  float sacc[2][4];
#pragma unroll
  for (int nt = 0; nt < 2; ++nt) {
    macc[nt] = (f32x4){-3e38f, -3e38f, -3e38f, -3e38f};
#pragma unroll
    for (int r = 0; r < 4; ++r) sacc[nt][r] = 0.f;
  }

  // ---- prologue: L1(0): x(0) -> h1
#pragma unroll
  for (int i = 0; i < 4; ++i) {
    const int pt = ph*4 + i;
    bf16x8 b = *(const bf16x8*)(&lds[LDSX + (pt*16 + l15)*40 + q*8]);
    f32x4 d = {0.f, 0.f, 0.f, 0.f};
    d = __builtin_amdgcn_mfma_f32_16x16x32_bf16(af1, b, d, 0, 0, 0);
    *(bf16x4*)(&lds[LDSH1 + (pt*16 + l15)*72 + c1t*16 + q*4]) = pack_relu4(d);
  }
  __syncthreads();                   // h1(0) ready; x(0) reads done

  for (int cg = 0; cg < 64; ++cg) {
    const int havenext = (cg < 63);

    // ==== Phase A: L2(cg): h1 -> h2, relu; stage x(cg+1) =================
    float pf0, pf1;
    if (havenext) {
      pf0 = pbase[(cg + 1)*768 + tid];
      if (i1v) pf1 = pbase[(cg + 1)*768 + 512 + tid];
    }
#pragma unroll
    for (int pt = 0; pt < 8; ++pt) {
      bf16x8 b0  = *(const bf16x8*)(&lds[LDSH1 + (pt*16 + l15)*72 + q*8]);
      bf16x8 b1v = *(const bf16x8*)(&lds[LDSH1 + (pt*16 + l15)*72 + 32 + q*8]);
      f32x4 d = bias2;
      d = __builtin_amdgcn_mfma_f32_16x16x32_bf16(af2[0], b0,  d, 0, 0, 0);
      d = __builtin_amdgcn_mfma_f32_16x16x32_bf16(af2[1], b1v, d, 0, 0, 0);
      *(bf16x4*)(&lds[LDSH2 + (pt*16 + l15)*136 + w*16 + q*4]) = pack_relu4(d);
    }
    // stage x(cg+1): x reads for L1(cg) finished before phase-B barrier of
    // the previous iteration (prologue barrier for cg=0)
    if (havenext) {
      lds[soff0] = f2bf(pf0);
      if (i1v) lds[soff1] = f2bf(pf1);
    }
    __syncthreads();                 // h2 ready; x(cg+1) visible; h1 reads done

    // ==== Phase B: L1(cg+1): x -> h1 ; L3(cg): h2 -> macc ===============
    if (havenext) {
#pragma unroll
      for (int i = 0; i < 4; ++i) {
        const int pt = ph*4 + i;
        bf16x8 b = *(const bf16x8*)(&lds[LDSX + (pt*16 + l15)*40 + q*8]);
        f32x4 d = {0.f, 0.f, 0.f, 0.f};
        d = __builtin_amdgcn_mfma_f32_16x16x32_bf16(af1, b, d, 0, 0, 0);
        *(bf16x4*)(&lds[LDSH1 + (pt*16 + l15)*72 + c1t*16 + q*4]) = pack_relu4(d);
      }
    }
#pragma unroll
    for (int pt = 0; pt < 8; ++pt) {
      bf16x8 b[4];
#pragma unroll
      for (int kf = 0; kf < 4; ++kf)
        b[kf] = *(const bf16x8*)(&lds[LDSH2 + (pt*16 + l15)*136 + kf*32 + q*8]);
#pragma unroll
      for (int nt = 0; nt < 2; ++nt) {
        f32x4 d = {0.f, 0.f, 0.f, 0.f};
#pragma unroll
        for (int kf = 0; kf < 4; ++kf)
          d = __builtin_amdgcn_mfma_f32_16x16x32_bf16(af3[nt][kf], b[kf], d, 0, 0, 0);
#pragma unroll
        for (int r = 0; r < 4; ++r)
          macc[nt][r] = fmaxf(macc[nt][r], d[r]);
      }
    }
    // part boundary (512 pts = 4 chunks): reduce max over the 16 pt-lanes
    if ((cg & 3) == 3) {
#pragma unroll
      for (int nt = 0; nt < 2; ++nt) {
#pragma unroll
        for (int r = 0; r < 4; ++r) {
          float v = macc[nt][r];
          v = fmaxf(v, __shfl_xor(v, 1));
          v = fmaxf(v, __shfl_xor(v, 2));
          v = fmaxf(v, __shfl_xor(v, 4));
          v = fmaxf(v, __shfl_xor(v, 8));
          sacc[nt][r] += v;
        }
        macc[nt] = (f32x4){-3e38f, -3e38f, -3e38f, -3e38f};
      }
    }
    __syncthreads();                 // h1(cg+1) ready; h2 reads done
  }

  // =========================================================================
  // In-block per-object MLP epilogue. LDS reused as float scratch:
  // fs[256] @0, bA[256] @256, bB[256] @512, part[2][256] @768, red[8] @1280.
  // Chain: fs -(We,+16be)-> bA -(Wg1,/16+bg1,relu)-> bB -(Wg2,+bg2)-> bA
  //        -(Wc1 src+dst,+bc1,relu)-> bB -(Wc2,+bc2,relu)-> bA -.Wc3-> tanh
  // =========================================================================
  float* fls  = (float*)&lds[0];
  float* fs   = fls;
  float* bA   = fls + 256;
  float* bB   = fls + 512;
  float* part = fls + 768;
  float* redv = fls + 1280;

  // fsum[ch] = sum_parts max + 16*b3 (bias3 folded post-max; 16 parts/object)
#pragma unroll
  for (int r = 0; r < 4; ++r) {
    if (l15 == r) {
#pragma unroll
      for (int nt = 0; nt < 2; ++nt) {
        const int ch = (2*w + nt)*16 + q*4 + r;
        fs[ch] = sacc[nt][r] + 16.f * b3f[ch];
      }
    }
  }
  __syncthreads();

  const int tt = tid & 255, hh = tid >> 8;
  const int cb = hh * 128;
  float a;

  // p1: bA = fs@We + 16*be
  a = 0.f;
#pragma unroll 8
  for (int c = 0; c < 128; ++c) a += fs[cb + c] * We[(cb + c)*256 + tt];
  part[hh*256 + tt] = a;
  __syncthreads();
  if (hh == 0) bA[tt] = part[tt] + part[256 + tt] + 16.f * be[tt];
  __syncthreads();

  // p2: bB = relu(bA@Wg1 / 16 + bg1)
  a = 0.f;
#pragma unroll 8
  for (int c = 0; c < 128; ++c) a += bA[cb + c] * Wg1[(cb + c)*256 + tt];
  part[hh*256 + tt] = a;
  __syncthreads();
  if (hh == 0) bB[tt] = fmaxf((part[tt] + part[256 + tt]) * 0.0625f + bg1[tt], 0.f);
  __syncthreads();

  // p3: bA = bB@Wg2 + bg2
  a = 0.f;
#pragma unroll 8
  for (int c = 0; c < 128; ++c) a += bB[cb + c] * Wg2[(cb + c)*256 + tt];
  part[hh*256 + tt] = a;
  __syncthreads();
  if (hh == 0) bA[tt] = part[tt] + part[256 + tt] + bg2[tt];
  __syncthreads();

  // p4: bB = relu(bA@(Wc1_src + Wc1_dst) + bc1)
  a = 0.f;
#pragma unroll 8
  for (int c = 0; c < 128; ++c) {
    const float xv = bA[cb + c];
    a += xv * Wc1[(cb + c)*256 + tt];
    a += xv * Wc1[(cb + c + 256)*256 + tt];
  }
  part[hh*256 + tt] = a;
  __syncthreads();
  if (hh == 0) bB[tt] = fmaxf(part[tt] + part[256 + tt] + bc1[tt], 0.f);
  __syncthreads();

  // p5: bA = relu(bB@Wc2 + bc2)
  a = 0.f;
#pragma unroll 8
  for (int c = 0; c < 128; ++c) a += bB[cb + c] * Wc2[(cb + c)*256 + tt];
  part[hh*256 + tt] = a;
  __syncthreads();
  if (hh == 0) bA[tt] = fmaxf(part[tt] + part[256 + tt] + bc2[tt], 0.f);
  __syncthreads();

  // p6: scalar = bA . Wc3; tanh; broadcast into 16x16 (zero diagonal)
  float prod = (hh == 0) ? bA[tt] * Wc3[tt] : 0.f;
#pragma unroll
  for (int off = 1; off < 64; off <<= 1) prod += __shfl_xor(prod, off);
  if (lane == 0) redv[w] = prod;
  __syncthreads();
  if (tid == 0) redv[0] = tanhf(redv[0] + redv[1] + redv[2] + redv[3] + bc3[0]);
  __syncthreads();
  const float cv = redv[0];
  if (hh == 0)
    out[obj*256 + tt] = ((tt >> 4) == (tt & 15)) ? 0.f : cv;
}

// ---------------------------------------------------------------------------
extern "C" void kernel_launch(void* const* d_in, const int* in_sizes, int n_in,
                              void* d_out, int out_size, void* d_ws, size_t ws_size,
                              hipStream_t stream) {
  const float* pcls = (const float*)d_in[0];
  const float* W1 = (const float*)d_in[1];  const float* b1 = (const float*)d_in[2];
  const float* g1 = (const float*)d_in[3];  const float* bt1 = (const float*)d_in[4];
  const float* W2 = (const float*)d_in[5];  const float* b2 = (const float*)d_in[6];
  const float* g2 = (const float*)d_in[7];  const float* bt2 = (const float*)d_in[8];
  const float* W3 = (const float*)d_in[9];  const float* b3 = (const float*)d_in[10];
  const float* g3 = (const float*)d_in[11]; const float* bt3 = (const float*)d_in[12];
  const float* We = (const float*)d_in[13]; const float* be = (const float*)d_in[14];
  const float* Wg1 = (const float*)d_in[15]; const float* bg1 = (const float*)d_in[16];
  const float* Wg2 = (const float*)d_in[17]; const float* bg2 = (const float*)d_in[18];
  const float* Wc1 = (const float*)d_in[19]; const float* bc1 = (const float*)d_in[20];
  const float* Wc2 = (const float*)d_in[21]; const float* bc2 = (const float*)d_in[22];
  const float* Wc3 = (const float*)d_in[23]; const float* bc3 = (const float*)d_in[24];
  unsigned char* ws = (unsigned char*)d_ws;
  float* out = (float*)d_out;

  prep_kernel<<<170, 256, 0, stream>>>(W1, b1, g1, bt1, W2, b2, g2, bt2,
                                       W3, b3, g3, bt3, ws);
  pointnet_fused_kernel<<<512, 512, 0, stream>>>(
      pcls, ws, We, be, Wg1, bg1, Wg2, bg2, Wc1, bc1, Wc2, bc2, Wc3, bc3, out);
}

// Round 2
// 482.395 us; speedup vs baseline: 1.0442x; 1.0442x over previous
//
#include <hip/hip_runtime.h>
#include <hip/hip_bf16.h>
#include <stdint.h>
#include <stddef.h>

// ---------------------------------------------------------------------------
// Connectivity3D: PointNet (6->64->128->256, BN folded, max-pool) ->
// object_embedding -> 2x GCN -> edge MLP -> tanh -> [512,16,16].
//
// Algebraic collapse: dense intra-object edges => deg=16 for every node =>
// GCN output = (per-object mean of xw) + b, identical for all 16 parts =>
// ONE edge score per object; only fsum[obj] = sum_parts feat is needed.
//
// R10 = LDS-read-pipe attack. R9 counters: 53.2K ds_read_b128/CU x ~12cyc
// = 639K cyc + 262K conflict cyc ~= the whole 920K-cyc kernel => the LDS
// read pipe IS the wall (MFMA 402K cyc overlaps on its own pipe).
//  - L2 re-tiled: wave = 2 ch-tiles x 4 pt-tiles -> 8 reads (was 16) for
//    the same 16 MFMAs (data:compute 1:4).
//  - sacc moved to LDS (fsacc[256]): frees 8 VGPRs to pay for af2[2][2].
//  - point staging: packed-dword writes (384 thr x float2 -> b32) instead
//    of 768 scalar b16 (kills same-dword 2-lane serialization).
// Reads/wave/iter 52 -> 44; register-neutral vs R9 (stays at the
// waves_per_eu(4,4) 128-unified ceiling without spilling).
// ---------------------------------------------------------------------------

typedef short bf16x8 __attribute__((ext_vector_type(8)));
typedef short bf16x4 __attribute__((ext_vector_type(4)));
typedef float f32x4  __attribute__((ext_vector_type(4)));

// workspace byte offsets (all 16B aligned)
#define WT1_OFF   0u        // bf16 [64][32]  (W1*g1)^T, col6 = bias, cols7-31 = 0
#define WT2_OFF   4096u     // bf16 [128][64] (W2*g2)^T
#define WT3_OFF   20480u    // bf16 [256][128](W3*g3)^T
#define B1F_OFF   86016u    // f32 [64] (unused; layout keep)
#define B2F_OFF   86272u    // f32 [128]
#define B3F_OFF   86784u    // f32 [256]

__device__ __forceinline__ unsigned short f2bf(float f) {
  union { float f; unsigned u; } v; v.f = f;
  unsigned r = v.u + 0x7fffu + ((v.u >> 16) & 1u);   // round-to-nearest-even
  return (unsigned short)(r >> 16);
}

__device__ __forceinline__ bf16x4 pack_relu4(f32x4 d) {
  __hip_bfloat162 lo = __float22bfloat162_rn(make_float2(fmaxf(d.x, 0.f), fmaxf(d.y, 0.f)));
  __hip_bfloat162 hi = __float22bfloat162_rn(make_float2(fmaxf(d.z, 0.f), fmaxf(d.w, 0.f)));
  union { bf16x4 v; __hip_bfloat162 h[2]; } u;
  u.h[0] = lo; u.h[1] = hi;
  return u.v;
}

// ---------------------------------------------------------------------------
__global__ void prep_kernel(
    const float* __restrict__ W1, const float* __restrict__ b1,
    const float* __restrict__ g1, const float* __restrict__ bt1,
    const float* __restrict__ W2, const float* __restrict__ b2,
    const float* __restrict__ g2, const float* __restrict__ bt2,
    const float* __restrict__ W3, const float* __restrict__ b3,
    const float* __restrict__ g3, const float* __restrict__ bt3,
    unsigned char* __restrict__ ws)
{
  unsigned short* wt1 = (unsigned short*)(ws + WT1_OFF);
  unsigned short* wt2 = (unsigned short*)(ws + WT2_OFF);
  unsigned short* wt3 = (unsigned short*)(ws + WT3_OFF);
  float* b1f  = (float*)(ws + B1F_OFF);
  float* b2f  = (float*)(ws + B2F_OFF);
  float* b3f  = (float*)(ws + B3F_OFF);

  int i = blockIdx.x * 256 + threadIdx.x;
  if (i < 2048) { int o = i >> 5, c = i & 31;                 // wt1[o][c]
    float v = (c < 6) ? W1[c*64 + o] * g1[o]
            : (c == 6 ? (b1[o]*g1[o] + bt1[o]) : 0.f);        // bias-in-col6
    wt1[i] = f2bf(v); return; }
  i -= 2048;
  if (i < 8192) { int o = i >> 6, c = i & 63;                 // wt2[o][c]
    wt2[i] = f2bf(W2[c*128 + o] * g2[o]); return; }
  i -= 8192;
  if (i < 32768) { int o = i >> 7, c = i & 127;               // wt3[o][c]
    wt3[i] = f2bf(W3[c*256 + o] * g3[o]); return; }
  i -= 32768;
  if (i < 64)  { b1f[i] = b1[i]*g1[i] + bt1[i]; return; }
  i -= 64;
  if (i < 128) { b2f[i] = b2[i]*g2[i] + bt2[i]; return; }
  i -= 128;
  if (i < 256) { b3f[i] = b3[i]*g3[i] + bt3[i]; }
}

// ---------------------------------------------------------------------------
// One block per object: 512 blocks x 512 thr (8 waves), 8192 pts, chunk=128,
// 64 iterations, 2 barriers/iter (R9 pipelined). Then in-block MLP epilogue
// (per-object GCN+connectivity head) and direct out write.
// LDS [pt][ch] bf16: x[128][40] @0, h1[128][72] @5120, h2[128][136] @14336
// fsacc f32[256] @short 31744 (byte 63488): per-object channel sums.
#define LDSX  0
#define LDSH1 5120
#define LDSH2 14336
#define LDSFS 31744   // short index of fsacc (f32[256])

__global__ __launch_bounds__(512)
__attribute__((amdgpu_waves_per_eu(4, 4)))
void pointnet_fused_kernel(
    const float* __restrict__ pcls, const unsigned char* __restrict__ ws,
    const float* __restrict__ We,  const float* __restrict__ be,
    const float* __restrict__ Wg1, const float* __restrict__ bg1,
    const float* __restrict__ Wg2, const float* __restrict__ bg2,
    const float* __restrict__ Wc1, const float* __restrict__ bc1,
    const float* __restrict__ Wc2, const float* __restrict__ bc2,
    const float* __restrict__ Wc3, const float* __restrict__ bc3,
    float* __restrict__ out)
{
  __shared__ __align__(16) unsigned short lds[32256];   // 64512 B -> 2 blocks/CU

  const unsigned short* wt1 = (const unsigned short*)(ws + WT1_OFF);
  const unsigned short* wt2 = (const unsigned short*)(ws + WT2_OFF);
  const unsigned short* wt3 = (const unsigned short*)(ws + WT3_OFF);
  const float* b2f = (const float*)(ws + B2F_OFF);
  const float* b3f = (const float*)(ws + B3F_OFF);

  const int tid  = threadIdx.x;
  const int w    = tid >> 6;        // wave 0..7
  const int lane = tid & 63;
  const int l15  = lane & 15;
  const int q    = lane >> 4;       // quad 0..3
  const int obj  = blockIdx.x;

  const int c1t = w & 3;            // L1 ch-tile
  const int ph  = w >> 2;           // L1 pt-half

  const int ct2 = (w & 3) * 2;      // L2 first ch-tile (pair ct2, ct2+1)
  const int pb2 = (w >> 2) * 4;     // L2 first pt-tile (4 tiles)

  // Weight A-fragments, register-resident. A[m=l15][k=q*8+j].
  bf16x8 af1 = *(const bf16x8*)(wt1 + (c1t*16 + l15)*32 + q*8);
  bf16x8 af2[2][2], af3[2][4];
#pragma unroll
  for (int ct = 0; ct < 2; ++ct)
#pragma unroll
    for (int kf = 0; kf < 2; ++kf)
      af2[ct][kf] = *(const bf16x8*)(wt2 + ((ct2 + ct)*16 + l15)*64 + kf*32 + q*8);
#pragma unroll
  for (int nt = 0; nt < 2; ++nt)
#pragma unroll
    for (int kf = 0; kf < 4; ++kf)
      af3[nt][kf] = *(const bf16x8*)(wt3 + ((2*w + nt)*16 + l15)*128 + kf*32 + q*8);

  f32x4 bs2[2];
#pragma unroll
  for (int ct = 0; ct < 2; ++ct)
    bs2[ct] = *(const f32x4*)(b2f + (ct2 + ct)*16 + q*4);

  // point staging: 768 floats/chunk; 384 threads each load a float2 and
  // write ONE packed dword (2 bf16) -> no same-dword write serialization.
  const int sv = tid < 384;
  const int sp = tid / 3;           // point within chunk  (tid<384)
  const int sc = tid % 3;           // dword index within row (ch pair)
  unsigned* ldsu = (unsigned*)lds;

  // init x: zeros, col6 = 1.0 (bias channel), cols 7..31 stay 0; fsacc = 0
  for (int i = tid; i < 5120; i += 512) lds[i] = 0;
  if (tid < 256) ((float*)&lds[LDSFS])[tid] = 0.f;
  __syncthreads();
  if (tid < 128) lds[LDSX + tid*40 + 6] = 0x3F80;   // bf16 1.0

  const float* pbase = pcls + (size_t)obj * 49152;   // 8192 pts * 6
  if (sv) {
    const float2 pv = *(const float2*)(pbase + 2*tid);
    ldsu[sp*20 + sc] = (unsigned)f2bf(pv.x) | ((unsigned)f2bf(pv.y) << 16);
  }
  __syncthreads();

  f32x4 macc[2];
#pragma unroll
  for (int nt = 0; nt < 2; ++nt)
    macc[nt] = (f32x4){-3e38f, -3e38f, -3e38f, -3e38f};

  // ---- prologue: L1(0): x(0) -> h1
#pragma unroll
  for (int i = 0; i < 4; ++i) {
    const int pt = ph*4 + i;
    bf16x8 b = *(const bf16x8*)(&lds[LDSX + (pt*16 + l15)*40 + q*8]);
    f32x4 d = {0.f, 0.f, 0.f, 0.f};
    d = __builtin_amdgcn_mfma_f32_16x16x32_bf16(af1, b, d, 0, 0, 0);
    *(bf16x4*)(&lds[LDSH1 + (pt*16 + l15)*72 + c1t*16 + q*4]) = pack_relu4(d);
  }
  __syncthreads();                   // h1(0) ready; x(0) reads done

  for (int cg = 0; cg < 64; ++cg) {
    const int havenext = (cg < 63);

    // ==== Phase A: L2(cg): h1 -> h2, relu; stage x(cg+1) =================
    float2 pv;
    if (havenext && sv)
      pv = *(const float2*)(pbase + (cg + 1)*768 + 2*tid);
#pragma unroll
    for (int pt = 0; pt < 4; ++pt) {
      const int ptt = pb2 + pt;
      bf16x8 b0  = *(const bf16x8*)(&lds[LDSH1 + (ptt*16 + l15)*72 + q*8]);
      bf16x8 b1v = *(const bf16x8*)(&lds[LDSH1 + (ptt*16 + l15)*72 + 32 + q*8]);
#pragma unroll
      for (int ct = 0; ct < 2; ++ct) {
        f32x4 d = bs2[ct];
        d = __builtin_amdgcn_mfma_f32_16x16x32_bf16(af2[ct][0], b0,  d, 0, 0, 0);
        d = __builtin_amdgcn_mfma_f32_16x16x32_bf16(af2[ct][1], b1v, d, 0, 0, 0);
        *(bf16x4*)(&lds[LDSH2 + (ptt*16 + l15)*136 + (ct2 + ct)*16 + q*4]) = pack_relu4(d);
      }
    }
    // stage x(cg+1): x reads for L1(cg) finished before phase-B barrier of
    // the previous iteration (prologue barrier for cg=0)
    if (havenext && sv)
      ldsu[sp*20 + sc] = (unsigned)f2bf(pv.x) | ((unsigned)f2bf(pv.y) << 16);
    __syncthreads();                 // h2 ready; x(cg+1) visible; h1 reads done

    // ==== Phase B: L1(cg+1): x -> h1 ; L3(cg): h2 -> macc ===============
    if (havenext) {
#pragma unroll
      for (int i = 0; i < 4; ++i) {
        const int pt = ph*4 + i;
        bf16x8 b = *(const bf16x8*)(&lds[LDSX + (pt*16 + l15)*40 + q*8]);
        f32x4 d = {0.f, 0.f, 0.f, 0.f};
        d = __builtin_amdgcn_mfma_f32_16x16x32_bf16(af1, b, d, 0, 0, 0);
        *(bf16x4*)(&lds[LDSH1 + (pt*16 + l15)*72 + c1t*16 + q*4]) = pack_relu4(d);
      }
    }
#pragma unroll
    for (int pt = 0; pt < 8; ++pt) {
      bf16x8 b[4];
#pragma unroll
      for (int kf = 0; kf < 4; ++kf)
        b[kf] = *(const bf16x8*)(&lds[LDSH2 + (pt*16 + l15)*136 + kf*32 + q*8]);
#pragma unroll
      for (int nt = 0; nt < 2; ++nt) {
        f32x4 d = {0.f, 0.f, 0.f, 0.f};
#pragma unroll
        for (int kf = 0; kf < 4; ++kf)
          d = __builtin_amdgcn_mfma_f32_16x16x32_bf16(af3[nt][kf], b[kf], d, 0, 0, 0);
#pragma unroll
        for (int r = 0; r < 4; ++r)
          macc[nt][r] = fmaxf(macc[nt][r], d[r]);
      }
    }
    // part boundary (512 pts = 4 chunks): reduce max over the 16 pt-lanes,
    // accumulate into LDS fsacc (unique writer per channel -> race-free)
    if ((cg & 3) == 3) {
      float* fsacc = (float*)&lds[LDSFS];
#pragma unroll
      for (int nt = 0; nt < 2; ++nt) {
#pragma unroll
        for (int r = 0; r < 4; ++r) {
          float v = macc[nt][r];
          v = fmaxf(v, __shfl_xor(v, 1));
          v = fmaxf(v, __shfl_xor(v, 2));
          v = fmaxf(v, __shfl_xor(v, 4));
          v = fmaxf(v, __shfl_xor(v, 8));
          if (l15 == 0) fsacc[(2*w + nt)*16 + q*4 + r] += v;
        }
        macc[nt] = (f32x4){-3e38f, -3e38f, -3e38f, -3e38f};
      }
    }
    __syncthreads();                 // h1(cg+1) ready; h2 reads done
  }

  // =========================================================================
  // In-block per-object MLP epilogue. LDS float scratch (x region reused):
  // bA[256] @0, bB[256] @256, part[2][256] @512, red[8] @1024.
  // fs = fsacc @ LDSFS already holds sum_parts(max); add 16*b3.
  // Chain: fs -(We,+16be)-> bA -(Wg1,/16+bg1,relu)-> bB -(Wg2,+bg2)-> bA
  //        -(Wc1 src+dst,+bc1,relu)-> bB -(Wc2,+bc2,relu)-> bA -.Wc3-> tanh
  // =========================================================================
  float* fls  = (float*)&lds[0];
  float* fs   = (float*)&lds[LDSFS];
  float* bA   = fls;
  float* bB   = fls + 256;
  float* part = fls + 512;
  float* redv = fls + 1024;

  if (tid < 256) fs[tid] += 16.f * b3f[tid];   // bias3 folded post-max
  __syncthreads();

  const int tt = tid & 255, hh = tid >> 8;
  const int cb = hh * 128;
  float a;

  // p1: bA = fs@We + 16*be
  a = 0.f;
#pragma unroll 8
  for (int c = 0; c < 128; ++c) a += fs[cb + c] * We[(cb + c)*256 + tt];
  part[hh*256 + tt] = a;
  __syncthreads();
  if (hh == 0) bA[tt] = part[tt] + part[256 + tt] + 16.f * be[tt];
  __syncthreads();

  // p2: bB = relu(bA@Wg1 / 16 + bg1)
  a = 0.f;
#pragma unroll 8
  for (int c = 0; c < 128; ++c) a += bA[cb + c] * Wg1[(cb + c)*256 + tt];
  part[hh*256 + tt] = a;
  __syncthreads();
  if (hh == 0) bB[tt] = fmaxf((part[tt] + part[256 + tt]) * 0.0625f + bg1[tt], 0.f);
  __syncthreads();

  // p3: bA = bB@Wg2 + bg2
  a = 0.f;
#pragma unroll 8
  for (int c = 0; c < 128; ++c) a += bB[cb + c] * Wg2[(cb + c)*256 + tt];
  part[hh*256 + tt] = a;
  __syncthreads();
  if (hh == 0) bA[tt] = part[tt] + part[256 + tt] + bg2[tt];
  __syncthreads();

  // p4: bB = relu(bA@(Wc1_src + Wc1_dst) + bc1)
  a = 0.f;
#pragma unroll 8
  for (int c = 0; c < 128; ++c) {
    const float xv = bA[cb + c];
    a += xv * Wc1[(cb + c)*256 + tt];
    a += xv * Wc1[(cb + c + 256)*256 + tt];
  }
  part[hh*256 + tt] = a;
  __syncthreads();
  if (hh == 0) bB[tt] = fmaxf(part[tt] + part[256 + tt] + bc1[tt], 0.f);
  __syncthreads();

  // p5: bA = relu(bB@Wc2 + bc2)
  a = 0.f;
#pragma unroll 8
  for (int c = 0; c < 128; ++c) a += bB[cb + c] * Wc2[(cb + c)*256 + tt];
  part[hh*256 + tt] = a;
  __syncthreads();
  if (hh == 0) bA[tt] = fmaxf(part[tt] + part[256 + tt] + bc2[tt], 0.f);
  __syncthreads();

  // p6: scalar = bA . Wc3; tanh; broadcast into 16x16 (zero diagonal)
  float prod = (hh == 0) ? bA[tt] * Wc3[tt] : 0.f;
#pragma unroll
  for (int off = 1; off < 64; off <<= 1) prod += __shfl_xor(prod, off);
  if (lane == 0) redv[w] = prod;
  __syncthreads();
  if (tid == 0) redv[0] = tanhf(redv[0] + redv[1] + redv[2] + redv[3] + bc3[0]);
  __syncthreads();
  const float cv = redv[0];
  if (hh == 0)
    out[obj*256 + tt] = ((tt >> 4) == (tt & 15)) ? 0.f : cv;
}

// ---------------------------------------------------------------------------
extern "C" void kernel_launch(void* const* d_in, const int* in_sizes, int n_in,
                              void* d_out, int out_size, void* d_ws, size_t ws_size,
                              hipStream_t stream) {
  const float* pcls = (const float*)d_in[0];
  const float* W1 = (const float*)d_in[1];  const float* b1 = (const float*)d_in[2];
  const float* g1 = (const float*)d_in[3];  const float* bt1 = (const float*)d_in[4];
  const float* W2 = (const float*)d_in[5];  const float* b2 = (const float*)d_in[6];
  const float* g2 = (const float*)d_in[7];  const float* bt2 = (const float*)d_in[8];
  const float* W3 = (const float*)d_in[9];  const float* b3 = (const float*)d_in[10];
  const float* g3 = (const float*)d_in[11]; const float* bt3 = (const float*)d_in[12];
  const float* We = (const float*)d_in[13]; const float* be = (const float*)d_in[14];
  const float* Wg1 = (const float*)d_in[15]; const float* bg1 = (const float*)d_in[16];
  const float* Wg2 = (const float*)d_in[17]; const float* bg2 = (const float*)d_in[18];
  const float* Wc1 = (const float*)d_in[19]; const float* bc1 = (const float*)d_in[20];
  const float* Wc2 = (const float*)d_in[21]; const float* bc2 = (const float*)d_in[22];
  const float* Wc3 = (const float*)d_in[23]; const float* bc3 = (const float*)d_in[24];
  unsigned char* ws = (unsigned char*)d_ws;
  float* out = (float*)d_out;

  prep_kernel<<<170, 256, 0, stream>>>(W1, b1, g1, bt1, W2, b2, g2, bt2,
                                       W3, b3, g3, bt3, ws);
  pointnet_fused_kernel<<<512, 512, 0, stream>>>(
      pcls, ws, We, be, Wg1, bg1, Wg2, bg2, Wc1, bc1, Wc2, bc2, Wc3, bc3, out);
}